// Round 7
// baseline (175.728 us; speedup 1.0000x reference)
//
#include <hip/hip_runtime.h>
#include <hip/hip_bf16.h>
#include <math.h>

#define EPS 1e-8f

constexpr int Bb = 8, Nn = 2048, Hh = 128;
constexpr int BN = Bb * Nn;      // 16384 rows per tensor
constexpr int CCH = 16;          // split-K chunks for matp
constexpr int TS = 280;          // T row stride (ushorts): 140 dw = 12 mod 32 banks

constexpr int REPS_MATP = 3;     // instrumentation: x3 idempotent inner reps
constexpr int REPS_FUSED = 3;

typedef __attribute__((ext_vector_type(8))) short bf16x8;
typedef __attribute__((ext_vector_type(4))) float f32x4;

#define MFMA16(a, b, c) __builtin_amdgcn_mfma_f32_16x16x32_bf16(a, b, c, 0, 0, 0)

static __device__ __forceinline__ ushort f2bf(float f) {
  union { __hip_bfloat16 h; ushort s; } u;
  u.h = __float2bfloat16(f);   // RNE
  return u.s;
}
static __device__ __forceinline__ float bf2f(ushort s) {
  union { float f; uint u; } u;
  u.u = ((uint)s) << 16;
  return u.f;
}
static __device__ __forceinline__ bf16x8 cvt8(const float* v) {
  bf16x8 r;
  #pragma unroll
  for (int i = 0; i < 4; i++) {
    union { __hip_bfloat162 h; short2 s; } u;
    u.h = __float22bfloat162_rn(make_float2(v[2 * i], v[2 * i + 1]));
    r[2 * i] = u.s.x; r[2 * i + 1] = u.s.y;
  }
  return r;
}
static __device__ __forceinline__ void split8(const float* v, bf16x8& hi, bf16x8& lo) {
  hi = cvt8(v);
  float res[8];
  #pragma unroll
  for (int i = 0; i < 8; i++) res[i] = v[i] - bf2f((ushort)hi[i]);
  lo = cvt8(res);
}

// ---------------------------------------------------------------------------
// matp128r — R4 body, x REPS_MATP idempotent inner reps (instrumentation).
// ---------------------------------------------------------------------------
__global__ __launch_bounds__(512) void matp128r_kernel(
    const float* __restrict__ h1, const float* __restrict__ h2,
    float* __restrict__ inv_out, float* __restrict__ Mpart) {
  __shared__ float xs[128 * 132];
  __shared__ ushort T[128 * TS];
  __shared__ float invs[128];
  __shared__ float sS[128];

  int idx = blockIdx.x;
  int chunk = idx & 15;
  int mb = idx >> 4;
  int b = mb & 7;
  int mat = mb >> 3;
  const float* src = (mat ? h2 : h1) + ((size_t)b * Nn + chunk * 128) * Hh;
  float* invp = inv_out + mat * BN + b * Nn + chunk * 128;
  int t = threadIdx.x;
  int lane = t & 63, w = t >> 6;
  int m = lane & 15, q = lane >> 4;

  #pragma unroll 1
  for (int rep = 0; rep < REPS_MATP; rep++) {
    __syncthreads();   // protect LDS vs prior rep's readers

    // stage 128 rows (8 x 512 float4) + in-flight norms
    #pragma unroll
    for (int i = 0; i < 8; i++) {
      int u = t + 512 * i;
      int r = u >> 5, c = (u & 31) << 2;
      float4 v = *(const float4*)(src + (size_t)r * Hh + c);
      *(float4*)&xs[r * 132 + c] = v;
      float ss = v.x * v.x + v.y * v.y + v.z * v.z + v.w * v.w;
      ss += __shfl_xor(ss, 1, 64);
      ss += __shfl_xor(ss, 2, 64);
      ss += __shfl_xor(ss, 4, 64);
      ss += __shfl_xor(ss, 8, 64);
      ss += __shfl_xor(ss, 16, 64);
      if ((lane & 31) == 0) {
        float inv = 1.0f / fmaxf(sqrtf(ss), EPS);
        invs[r] = inv;
        sS[r] = sqrtf(inv);
      }
    }
    __syncthreads();

    // transpose + scale + split: T[c][n hi 0..127 | n lo 128..255]
    {
      int c = t & 127, rh = t >> 7;
      #pragma unroll
      for (int j = 0; j < 16; j++) {
        int r0 = rh * 32 + 2 * j;
        float v0 = xs[r0 * 132 + c] * sS[r0];
        float v1 = xs[(r0 + 1) * 132 + c] * sS[r0 + 1];
        ushort hh0 = f2bf(v0), hh1 = f2bf(v1);
        ushort ll0 = f2bf(v0 - bf2f(hh0)), ll1 = f2bf(v1 - bf2f(hh1));
        ushort2 uh; uh.x = hh0; uh.y = hh1;
        ushort2 ul; ul.x = ll0; ul.y = ll1;
        *(ushort2*)&T[c * TS + r0] = uh;
        *(ushort2*)&T[c * TS + 128 + r0] = ul;
      }
    }
    __syncthreads();

    // GEMM: wave w owns M rows [w*16, w*16+16)
    f32x4 acc[8];
    #pragma unroll
    for (int tc = 0; tc < 8; tc++) acc[tc] = (f32x4){0.f, 0.f, 0.f, 0.f};
    #pragma unroll
    for (int ks = 0; ks < 4; ks++) {
      int n0 = ks * 32 + q * 8;
      int cA = w * 16 + m;
      bf16x8 Ah = *(bf16x8*)&T[cA * TS + n0];
      bf16x8 Al = *(bf16x8*)&T[cA * TS + 128 + n0];
      #pragma unroll
      for (int tc = 0; tc < 8; tc++) {
        int cB = tc * 16 + m;
        bf16x8 Bh = *(bf16x8*)&T[cB * TS + n0];
        bf16x8 Bl = *(bf16x8*)&T[cB * TS + 128 + n0];
        acc[tc] = MFMA16(Ah, Bh, acc[tc]);
        acc[tc] = MFMA16(Ah, Bl, acc[tc]);
        acc[tc] = MFMA16(Al, Bh, acc[tc]);
      }
    }
    if (t < 128) invp[t] = invs[t];
    float* outp = Mpart + ((size_t)mb * CCH + chunk) * 16384;
    #pragma unroll
    for (int tc = 0; tc < 8; tc++)
      #pragma unroll
      for (int rg = 0; rg < 4; rg++) {
        int row = w * 16 + q * 4 + rg;
        outp[row * 128 + tc * 16 + m] = acc[tc][rg];
      }
  }
}

// ---------------------------------------------------------------------------
// matr: reduce partials -> Mi hi/lo (unchanged, x1)
// ---------------------------------------------------------------------------
__global__ __launch_bounds__(256) void matr_kernel(const float* __restrict__ Mpart,
                                                   ushort* __restrict__ Mi) {
  int gid = blockIdx.x * 256 + threadIdx.x;   // 16*16384
  int mb = gid >> 14;
  int e = gid & 16383;
  int k = e >> 7, h = e & 127;
  const float* p = Mpart + (size_t)mb * CCH * 16384 + e;
  float s = 0.f;
  #pragma unroll
  for (int c = 0; c < CCH; c++) s += p[(size_t)c * 16384];
  ushort hi = f2bf(s);
  Mi[(size_t)mb * 32768 + k * 256 + h] = hi;
  Mi[(size_t)mb * 32768 + k * 256 + 128 + h] = f2bf(s - bf2f(hi));
}

// ---------------------------------------------------------------------------
// fused2r — R4 body (512 threads, 128 rows, z-swap + wave scratch),
// x REPS_FUSED idempotent inner reps (instrumentation).
// ---------------------------------------------------------------------------
__global__ __launch_bounds__(512) void fused2r_kernel(
    const float* __restrict__ h1, const float* __restrict__ h2,
    const float* __restrict__ inv, const ushort* __restrict__ Mi,
    const float* __restrict__ wm, float* __restrict__ out) {
  __shared__ ushort T[128 * TS];       // 71,680 B
  __shared__ float sc[8 * 16 * 36];    // 18,432 B wave-private y scratch

  int g0 = blockIdx.x * 128;
  int which = g0 >> 14, b = (g0 >> 11) & 7, n0 = g0 & 2047;
  const float* xsrc = which ? h2 : h1;
  const ushort* Msrc = Mi + (size_t)((which ^ 1) * 8 + b) * 32768;
  int t = threadIdx.x;
  int lane = t & 63, m = lane & 15, q = lane >> 4;
  int w = t >> 6, rb = w * 16;
  const float* xrow = xsrc + ((size_t)b * Nn + n0 + rb + m) * Hh;
  float inv_m = inv[which * BN + b * Nn + n0 + rb + m];
  float* ob = out + (size_t)g0 * Hh;

  #pragma unroll 1
  for (int rep = 0; rep < REPS_FUSED; rep++) {
    __syncthreads();   // protect T vs prior rep's phase-2 readers

    // stage Mi -> T (bank-conflict-free b128 pattern)
    #pragma unroll
    for (int i = 0; i < 8; i++) {
      int u = t + 512 * i;
      int row = u >> 5, seg = u & 31;
      *(bf16x8*)&T[row * TS + seg * 8] = *(const bf16x8*)&Msrc[u * 8];
    }

    float xv[4][8];
    #pragma unroll
    for (int ks = 0; ks < 4; ks++) {
      int k0 = ks * 32 + q * 8;
      *(float4*)&xv[ks][0] = *(const float4*)(xrow + k0);
      *(float4*)&xv[ks][4] = *(const float4*)(xrow + k0 + 4);
    }
    __syncthreads();   // T(Mi) staged

    // ---- phase 1 (transposed): thread (m,q) ends with its own row's y
    f32x4 z[8];
    #pragma unroll
    for (int nt = 0; nt < 8; nt++) z[nt] = (f32x4){0.f, 0.f, 0.f, 0.f};
    #pragma unroll
    for (int ks = 0; ks < 4; ks++) {
      int k0 = ks * 32 + q * 8;
      bf16x8 xh, xl;
      split8(xv[ks], xh, xl);
      #pragma unroll
      for (int nt = 0; nt < 8; nt++) {
        int cB = nt * 16 + m;
        bf16x8 Bh = *(bf16x8*)&T[cB * TS + k0];
        bf16x8 Bl = *(bf16x8*)&T[cB * TS + 128 + k0];
        z[nt] = MFMA16(Bh, xh, z[nt]);
        z[nt] = MFMA16(Bl, xh, z[nt]);
        z[nt] = MFMA16(Bh, xl, z[nt]);
      }
    }

    // ---- wave-private k-relayout: z (C-layout) -> yv (A-frag layout)
    float yv[4][8];
    {
      float* srow = &sc[(w * 16 + m) * 36];
      #pragma unroll
      for (int ks = 0; ks < 4; ks++) {
        f32x4 e = z[2 * ks] * inv_m;       // k-offsets  0..15
        f32x4 o = z[2 * ks + 1] * inv_m;   // k-offsets 16..31
        *(f32x4*)&srow[q * 4] = e;
        *(f32x4*)&srow[16 + q * 4] = o;
        f32x4 r0 = *(f32x4*)&srow[q * 8];
        f32x4 r1 = *(f32x4*)&srow[q * 8 + 4];
        #pragma unroll
        for (int i = 0; i < 4; i++) { yv[ks][i] = r0[i]; yv[ks][4 + i] = r1[i]; }
      }
    }
    __syncthreads();   // everyone done reading T(Mi)

    // T <- W2 = wm^2 (hi/lo split)
    #pragma unroll
    for (int i = 0; i < 16; i++) {
      int u = t + 512 * i;
      int r = u >> 6, c = (u & 63) * 2;
      float2 w2 = *(const float2*)(wm + r * 128 + c);
      float v0 = w2.x * w2.x, v1 = w2.y * w2.y;
      ushort hh0 = f2bf(v0), hh1 = f2bf(v1);
      ushort ll0 = f2bf(v0 - bf2f(hh0)), ll1 = f2bf(v1 - bf2f(hh1));
      ushort2 uh; uh.x = hh0; uh.y = hh1;
      ushort2 ul; ul.x = ll0; ul.y = ll1;
      *(ushort2*)&T[r * TS + c] = uh;
      *(ushort2*)&T[r * TS + 128 + c] = ul;
    }
    __syncthreads();

    // ---- phase 2: fm epilogue
    f32x4 aN[8], aX[8], aY[8];
    #pragma unroll
    for (int nt = 0; nt < 8; nt++) {
      aN[nt] = (f32x4){0.f, 0.f, 0.f, 0.f};
      aX[nt] = (f32x4){0.f, 0.f, 0.f, 0.f};
      aY[nt] = (f32x4){0.f, 0.f, 0.f, 0.f};
    }
    #pragma unroll
    for (int ks = 0; ks < 4; ks++) {
      int k0 = ks * 32 + q * 8;
      float pxy[8], pxx[8], pyy[8];
      #pragma unroll
      for (int i = 0; i < 8; i++) {
        float xf = xv[ks][i], yf = yv[ks][i];
        pxy[i] = xf * yf;
        pxx[i] = xf * xf;
        pyy[i] = yf * yf;
      }
      bf16x8 xyh, xyl;
      split8(pxy, xyh, xyl);
      bf16x8 xxh = cvt8(pxx);
      bf16x8 yyh = cvt8(pyy);
      #pragma unroll
      for (int nt = 0; nt < 8; nt++) {
        int cB = nt * 16 + m;
        bf16x8 wh = *(bf16x8*)&T[cB * TS + k0];
        bf16x8 wl = *(bf16x8*)&T[cB * TS + 128 + k0];
        aN[nt] = MFMA16(xyh, wh, aN[nt]);
        aN[nt] = MFMA16(xyh, wl, aN[nt]);
        aN[nt] = MFMA16(xyl, wh, aN[nt]);
        aX[nt] = MFMA16(xxh, wh, aX[nt]);
        aX[nt] = MFMA16(xxh, wl, aX[nt]);
        aY[nt] = MFMA16(yyh, wh, aY[nt]);
        aY[nt] = MFMA16(yyh, wl, aY[nt]);
      }
    }

    #pragma unroll
    for (int nt = 0; nt < 8; nt++)
      #pragma unroll
      for (int rg = 0; rg < 4; rg++) {
        int row = rb + q * 4 + rg;
        float dx = fmaxf(sqrtf(fmaxf(aX[nt][rg], 0.f)), EPS);
        float dy = fmaxf(sqrtf(fmaxf(aY[nt][rg], 0.f)), EPS);
        ob[(size_t)row * Hh + nt * 16 + m] = aN[nt][rg] / (dx * dy);
      }
  }
}

// ---------------------------------------------------------------------------
extern "C" void kernel_launch(void* const* d_in, const int* in_sizes, int n_in,
                              void* d_out, int out_size, void* d_ws, size_t ws_size,
                              hipStream_t stream) {
  const float* h1 = (const float*)d_in[0];
  const float* h2 = (const float*)d_in[1];
  const float* wm = (const float*)d_in[2];
  float* out = (float*)d_out;

  char* ws = (char*)d_ws;
  float* inv   = (float*)ws;                 // 2*16384*4    = 131072 B
  ushort* Mi   = (ushort*)(ws + 131072);     // 16*32768*2   = 1 MiB
  float* Mpart = (float*)(ws + 1179648);     // 16*16*16384*4 = 16 MiB

  matp128r_kernel<<<16 * CCH, 512, 0, stream>>>(h1, h2, inv, Mpart);
  matr_kernel<<<16 * 16384 / 256, 256, 0, stream>>>(Mpart, Mi);
  fused2r_kernel<<<2 * BN / 128, 512, 0, stream>>>(h1, h2, inv, Mi, wm, out);
}

// Round 8
// 105.337 us; speedup vs baseline: 1.6682x; 1.6682x over previous
//
#include <hip/hip_runtime.h>
#include <hip/hip_bf16.h>
#include <math.h>

#define EPS 1e-8f

constexpr int Bb = 8, Nn = 2048, Hh = 128;
constexpr int BN = Bb * Nn;      // 16384 rows per tensor
constexpr int CCH = 16;          // split-K chunks for matp
constexpr int TS = 280;          // T row stride (ushorts): 140 dw = 12 mod 32 banks

typedef __attribute__((ext_vector_type(8))) short bf16x8;
typedef __attribute__((ext_vector_type(4))) float f32x4;

#define MFMA16(a, b, c) __builtin_amdgcn_mfma_f32_16x16x32_bf16(a, b, c, 0, 0, 0)

static __device__ __forceinline__ ushort f2bf(float f) {
  union { __hip_bfloat16 h; ushort s; } u;
  u.h = __float2bfloat16(f);   // RNE
  return u.s;
}
static __device__ __forceinline__ float bf2f(ushort s) {
  union { float f; uint u; } u;
  u.u = ((uint)s) << 16;
  return u.f;
}
static __device__ __forceinline__ bf16x8 cvt8(const float* v) {
  bf16x8 r;
  #pragma unroll
  for (int i = 0; i < 4; i++) {
    union { __hip_bfloat162 h; short2 s; } u;
    u.h = __float22bfloat162_rn(make_float2(v[2 * i], v[2 * i + 1]));
    r[2 * i] = u.s.x; r[2 * i + 1] = u.s.y;
  }
  return r;
}
static __device__ __forceinline__ void split8(const float* v, bf16x8& hi, bf16x8& lo) {
  hi = cvt8(v);
  float res[8];
  #pragma unroll
  for (int i = 0; i < 8; i++) res[i] = v[i] - bf2f((ushort)hi[i]);
  lo = cvt8(res);
}

// ---------------------------------------------------------------------------
// Kernel 1: matp — R4 body (in-flight norms), unchanged.
// ---------------------------------------------------------------------------
__global__ __launch_bounds__(512) void matp_kernel(const float* __restrict__ h1,
                                                   const float* __restrict__ h2,
                                                   float* __restrict__ inv_out,
                                                   float* __restrict__ Mpart) {
  __shared__ float xs[128 * 132];
  __shared__ ushort T[128 * TS];
  __shared__ float invs[128];
  __shared__ float sS[128];

  int idx = blockIdx.x;
  int chunk = idx & 15;
  int mb = idx >> 4;
  int b = mb & 7;
  int mat = mb >> 3;
  const float* src = (mat ? h2 : h1) + ((size_t)b * Nn + chunk * 128) * Hh;
  float* invp = inv_out + mat * BN + b * Nn + chunk * 128;
  int t = threadIdx.x;
  int lane = t & 63, w = t >> 6;
  int m = lane & 15, q = lane >> 4;

  // stage 128 rows (8 x 512 float4) + in-flight norms
  #pragma unroll
  for (int i = 0; i < 8; i++) {
    int u = t + 512 * i;
    int r = u >> 5, c = (u & 31) << 2;
    float4 v = *(const float4*)(src + (size_t)r * Hh + c);
    *(float4*)&xs[r * 132 + c] = v;
    float ss = v.x * v.x + v.y * v.y + v.z * v.z + v.w * v.w;
    ss += __shfl_xor(ss, 1, 64);
    ss += __shfl_xor(ss, 2, 64);
    ss += __shfl_xor(ss, 4, 64);
    ss += __shfl_xor(ss, 8, 64);
    ss += __shfl_xor(ss, 16, 64);
    if ((lane & 31) == 0) {
      float inv = 1.0f / fmaxf(sqrtf(ss), EPS);
      invs[r] = inv;
      sS[r] = sqrtf(inv);
    }
  }
  __syncthreads();

  // transpose + scale + split: T[c][n hi 0..127 | n lo 128..255]
  {
    int c = t & 127, rh = t >> 7;
    #pragma unroll
    for (int j = 0; j < 16; j++) {
      int r0 = rh * 32 + 2 * j;
      float v0 = xs[r0 * 132 + c] * sS[r0];
      float v1 = xs[(r0 + 1) * 132 + c] * sS[r0 + 1];
      ushort hh0 = f2bf(v0), hh1 = f2bf(v1);
      ushort ll0 = f2bf(v0 - bf2f(hh0)), ll1 = f2bf(v1 - bf2f(hh1));
      ushort2 uh; uh.x = hh0; uh.y = hh1;
      ushort2 ul; ul.x = ll0; ul.y = ll1;
      *(ushort2*)&T[c * TS + r0] = uh;
      *(ushort2*)&T[c * TS + 128 + r0] = ul;
    }
  }
  __syncthreads();

  // GEMM: wave w owns M rows [w*16, w*16+16)
  f32x4 acc[8];
  #pragma unroll
  for (int tc = 0; tc < 8; tc++) acc[tc] = (f32x4){0.f, 0.f, 0.f, 0.f};
  #pragma unroll
  for (int ks = 0; ks < 4; ks++) {
    int n0 = ks * 32 + q * 8;
    int cA = w * 16 + m;
    bf16x8 Ah = *(bf16x8*)&T[cA * TS + n0];
    bf16x8 Al = *(bf16x8*)&T[cA * TS + 128 + n0];
    #pragma unroll
    for (int tc = 0; tc < 8; tc++) {
      int cB = tc * 16 + m;
      bf16x8 Bh = *(bf16x8*)&T[cB * TS + n0];
      bf16x8 Bl = *(bf16x8*)&T[cB * TS + 128 + n0];
      acc[tc] = MFMA16(Ah, Bh, acc[tc]);
      acc[tc] = MFMA16(Ah, Bl, acc[tc]);
      acc[tc] = MFMA16(Al, Bh, acc[tc]);
    }
  }
  if (t < 128) invp[t] = invs[t];
  float* outp = Mpart + ((size_t)mb * CCH + chunk) * 16384;
  #pragma unroll
  for (int tc = 0; tc < 8; tc++)
    #pragma unroll
    for (int rg = 0; rg < 4; rg++) {
      int row = w * 16 + q * 4 + rg;
      outp[row * 128 + tc * 16 + m] = acc[tc][rg];
    }
}

// ---------------------------------------------------------------------------
// Kernel 2: matr — reduce partials -> Mi hi/lo; blocks >= 1024 additionally
// precompute the W2 = wm^2 hi/lo split into W2s (same LDS-ready layout), so
// fused2's W2 staging becomes a pure bf16x8 copy.
// ---------------------------------------------------------------------------
__global__ __launch_bounds__(256) void matr_kernel(const float* __restrict__ Mpart,
                                                   const float* __restrict__ wm,
                                                   ushort* __restrict__ Mi,
                                                   ushort* __restrict__ W2s) {
  int bid = blockIdx.x;
  if (bid >= 1024) {
    int g2 = (bid - 1024) * 256 + threadIdx.x;   // 0..16383
    int r = g2 >> 7, c = g2 & 127;
    float v = wm[g2];
    float v2 = v * v;
    ushort hi = f2bf(v2);
    W2s[r * 256 + c] = hi;
    W2s[r * 256 + 128 + c] = f2bf(v2 - bf2f(hi));
    return;
  }
  int gid = bid * 256 + threadIdx.x;   // 16*16384
  int mb = gid >> 14;
  int e = gid & 16383;
  int k = e >> 7, h = e & 127;
  const float* p = Mpart + (size_t)mb * CCH * 16384 + e;
  float s = 0.f;
  #pragma unroll
  for (int c = 0; c < CCH; c++) s += p[(size_t)c * 16384];
  ushort hi = f2bf(s);
  Mi[(size_t)mb * 32768 + k * 256 + h] = hi;
  Mi[(size_t)mb * 32768 + k * 256 + 128 + h] = f2bf(s - bf2f(hi));
}

// ---------------------------------------------------------------------------
// Kernel 3: fused2 — SINGLE-BARRIER restructure. Mi-T and W2-T are both
// resident in LDS (71,680 x 2 + 18,432 scratch = 161,792 B <= 160 KiB), both
// staged up front; after one barrier, phase1 MFMAs (T1), wave-private
// relayout, and phase2 MFMAs (T2) form one unfenced dependence region — the
// compiler can interleave phase2's x*x MFMAs (independent of phase1) freely.
// ---------------------------------------------------------------------------
__global__ __launch_bounds__(512) void fused2_kernel(
    const float* __restrict__ h1, const float* __restrict__ h2,
    const float* __restrict__ inv, const ushort* __restrict__ Mi,
    const ushort* __restrict__ W2s, float* __restrict__ out) {
  __shared__ __align__(16) char ldsb[161792];
  ushort* T1 = (ushort*)ldsb;              // [128*TS] Mi  (71,680 B)
  ushort* T2 = (ushort*)(ldsb + 71680);    // [128*TS] W2  (71,680 B)
  float* sc  = (float*)(ldsb + 143360);    // [8*16*36]    (18,432 B)

  int g0 = blockIdx.x * 128;
  int which = g0 >> 14, b = (g0 >> 11) & 7, n0 = g0 & 2047;
  const float* xsrc = which ? h2 : h1;
  const ushort* Msrc = Mi + (size_t)((which ^ 1) * 8 + b) * 32768;
  int t = threadIdx.x;

  // stage Mi -> T1 and W2s -> T2 (both pure bf16x8 copies, same pattern)
  #pragma unroll
  for (int i = 0; i < 8; i++) {
    int u = t + 512 * i;
    int row = u >> 5, seg = u & 31;
    *(bf16x8*)&T1[row * TS + seg * 8] = *(const bf16x8*)&Msrc[u * 8];
    *(bf16x8*)&T2[row * TS + seg * 8] = *(const bf16x8*)&W2s[u * 8];
  }

  int lane = t & 63, m = lane & 15, q = lane >> 4;
  int w = t >> 6, rb = w * 16;
  const float* xrow = xsrc + ((size_t)b * Nn + n0 + rb + m) * Hh;
  float inv_m = inv[which * BN + b * Nn + n0 + rb + m];

  float xv[4][8];
  #pragma unroll
  for (int ks = 0; ks < 4; ks++) {
    int k0 = ks * 32 + q * 8;
    *(float4*)&xv[ks][0] = *(const float4*)(xrow + k0);
    *(float4*)&xv[ks][4] = *(const float4*)(xrow + k0 + 4);
  }
  __syncthreads();   // the ONLY barrier

  // ---- phase 1 (transposed): thread (m,q) ends with its own row's y values
  f32x4 z[8];
  #pragma unroll
  for (int nt = 0; nt < 8; nt++) z[nt] = (f32x4){0.f, 0.f, 0.f, 0.f};
  #pragma unroll
  for (int ks = 0; ks < 4; ks++) {
    int k0 = ks * 32 + q * 8;
    bf16x8 xh, xl;
    split8(xv[ks], xh, xl);
    #pragma unroll
    for (int nt = 0; nt < 8; nt++) {
      int cB = nt * 16 + m;
      bf16x8 Bh = *(bf16x8*)&T1[cB * TS + k0];
      bf16x8 Bl = *(bf16x8*)&T1[cB * TS + 128 + k0];
      z[nt] = MFMA16(Bh, xh, z[nt]);
      z[nt] = MFMA16(Bl, xh, z[nt]);
      z[nt] = MFMA16(Bh, xl, z[nt]);
    }
  }

  // ---- wave-private k-relayout: z (C-layout) -> yv (A-frag layout) ----
  float yv[4][8];
  {
    float* srow = &sc[(w * 16 + m) * 36];
    #pragma unroll
    for (int ks = 0; ks < 4; ks++) {
      f32x4 e = z[2 * ks] * inv_m;       // k-offsets  0..15
      f32x4 o = z[2 * ks + 1] * inv_m;   // k-offsets 16..31
      *(f32x4*)&srow[q * 4] = e;
      *(f32x4*)&srow[16 + q * 4] = o;
      f32x4 r0 = *(f32x4*)&srow[q * 8];
      f32x4 r1 = *(f32x4*)&srow[q * 8 + 4];
      #pragma unroll
      for (int i = 0; i < 4; i++) { yv[ks][i] = r0[i]; yv[ks][4 + i] = r1[i]; }
    }
  }

  // ---- phase 2: fm epilogue (reads T2; no barrier needed) ----
  f32x4 aN[8], aX[8], aY[8];
  #pragma unroll
  for (int nt = 0; nt < 8; nt++) {
    aN[nt] = (f32x4){0.f, 0.f, 0.f, 0.f};
    aX[nt] = (f32x4){0.f, 0.f, 0.f, 0.f};
    aY[nt] = (f32x4){0.f, 0.f, 0.f, 0.f};
  }
  #pragma unroll
  for (int ks = 0; ks < 4; ks++) {
    int k0 = ks * 32 + q * 8;
    float pxy[8], pxx[8], pyy[8];
    #pragma unroll
    for (int i = 0; i < 8; i++) {
      float xf = xv[ks][i], yf = yv[ks][i];
      pxy[i] = xf * yf;
      pxx[i] = xf * xf;
      pyy[i] = yf * yf;
    }
    bf16x8 xyh, xyl;
    split8(pxy, xyh, xyl);
    bf16x8 xxh = cvt8(pxx);
    bf16x8 yyh = cvt8(pyy);
    #pragma unroll
    for (int nt = 0; nt < 8; nt++) {
      int cB = nt * 16 + m;
      bf16x8 wh = *(bf16x8*)&T2[cB * TS + k0];
      bf16x8 wl = *(bf16x8*)&T2[cB * TS + 128 + k0];
      aN[nt] = MFMA16(xyh, wh, aN[nt]);
      aN[nt] = MFMA16(xyh, wl, aN[nt]);
      aN[nt] = MFMA16(xyl, wh, aN[nt]);
      aX[nt] = MFMA16(xxh, wh, aX[nt]);
      aX[nt] = MFMA16(xxh, wl, aX[nt]);
      aY[nt] = MFMA16(yyh, wh, aY[nt]);
      aY[nt] = MFMA16(yyh, wl, aY[nt]);
    }
  }

  float* ob = out + (size_t)g0 * Hh;
  #pragma unroll
  for (int nt = 0; nt < 8; nt++)
    #pragma unroll
    for (int rg = 0; rg < 4; rg++) {
      int row = rb + q * 4 + rg;
      float dx = fmaxf(sqrtf(fmaxf(aX[nt][rg], 0.f)), EPS);
      float dy = fmaxf(sqrtf(fmaxf(aY[nt][rg], 0.f)), EPS);
      ob[(size_t)row * Hh + nt * 16 + m] = aN[nt][rg] / (dx * dy);
    }
}

// ---------------------------------------------------------------------------
extern "C" void kernel_launch(void* const* d_in, const int* in_sizes, int n_in,
                              void* d_out, int out_size, void* d_ws, size_t ws_size,
                              hipStream_t stream) {
  const float* h1 = (const float*)d_in[0];
  const float* h2 = (const float*)d_in[1];
  const float* wm = (const float*)d_in[2];
  float* out = (float*)d_out;

  char* ws = (char*)d_ws;
  float* inv   = (float*)ws;                 // 2*16384*4    = 131072 B
  ushort* Mi   = (ushort*)(ws + 131072);     // 16*32768*2   = 1 MiB
  ushort* W2s  = (ushort*)(ws + 1179648);    // 128*256*2    = 65536 B
  float* Mpart = (float*)(ws + 1245184);     // 16*16*16384*4 = 16 MiB

  matp_kernel<<<16 * CCH, 512, 0, stream>>>(h1, h2, inv, Mpart);
  matr_kernel<<<1024 + 64, 256, 0, stream>>>(Mpart, wm, Mi, W2s);
  fused2_kernel<<<2 * BN / 128, 512, 0, stream>>>(h1, h2, inv, Mi, W2s, out);
}

// Round 9
// 101.846 us; speedup vs baseline: 1.7254x; 1.0343x over previous
//
#include <hip/hip_runtime.h>
#include <hip/hip_bf16.h>
#include <math.h>

#define EPS 1e-8f

constexpr int Bb = 8, Nn = 2048, Hh = 128;
constexpr int BN = Bb * Nn;      // 16384 rows per tensor
constexpr int CCH = 16;          // split-K chunks for matp
constexpr int TSM = 280;         // matp T stride (ushorts), as before
constexpr int TS  = 288;         // fused2 T / Mi_pad stride: 144 dw; b128 reads
                                 // start-bank 4*(16(m&1)... = 8 even groups (min);
                                 // 128*288*2 = 73728 B = 9 * (512 thr * 16 B) exact

typedef __attribute__((ext_vector_type(8))) short bf16x8;
typedef __attribute__((ext_vector_type(4))) float f32x4;

#define MFMA16(a, b, c) __builtin_amdgcn_mfma_f32_16x16x32_bf16(a, b, c, 0, 0, 0)

static __device__ __forceinline__ ushort f2bf(float f) {
  union { __hip_bfloat16 h; ushort s; } u;
  u.h = __float2bfloat16(f);   // RNE
  return u.s;
}
static __device__ __forceinline__ float bf2f(ushort s) {
  union { float f; uint u; } u;
  u.u = ((uint)s) << 16;
  return u.f;
}
static __device__ __forceinline__ bf16x8 cvt8(const float* v) {
  bf16x8 r;
  #pragma unroll
  for (int i = 0; i < 4; i++) {
    union { __hip_bfloat162 h; short2 s; } u;
    u.h = __float22bfloat162_rn(make_float2(v[2 * i], v[2 * i + 1]));
    r[2 * i] = u.s.x; r[2 * i + 1] = u.s.y;
  }
  return r;
}
static __device__ __forceinline__ void split8(const float* v, bf16x8& hi, bf16x8& lo) {
  hi = cvt8(v);
  float res[8];
  #pragma unroll
  for (int i = 0; i < 8; i++) res[i] = v[i] - bf2f((ushort)hi[i]);
  lo = cvt8(res);
}

// ---------------------------------------------------------------------------
// Kernel 1: matp — R4 body exactly (in-flight norms), proven best.
// ---------------------------------------------------------------------------
__global__ __launch_bounds__(512) void matp_kernel(const float* __restrict__ h1,
                                                   const float* __restrict__ h2,
                                                   float* __restrict__ inv_out,
                                                   float* __restrict__ Mpart) {
  __shared__ float xs[128 * 132];
  __shared__ ushort T[128 * TSM];
  __shared__ float invs[128];
  __shared__ float sS[128];

  int idx = blockIdx.x;
  int chunk = idx & 15;
  int mb = idx >> 4;
  int b = mb & 7;
  int mat = mb >> 3;
  const float* src = (mat ? h2 : h1) + ((size_t)b * Nn + chunk * 128) * Hh;
  float* invp = inv_out + mat * BN + b * Nn + chunk * 128;
  int t = threadIdx.x;
  int lane = t & 63, w = t >> 6;
  int m = lane & 15, q = lane >> 4;

  #pragma unroll
  for (int i = 0; i < 8; i++) {
    int u = t + 512 * i;
    int r = u >> 5, c = (u & 31) << 2;
    float4 v = *(const float4*)(src + (size_t)r * Hh + c);
    *(float4*)&xs[r * 132 + c] = v;
    float ss = v.x * v.x + v.y * v.y + v.z * v.z + v.w * v.w;
    ss += __shfl_xor(ss, 1, 64);
    ss += __shfl_xor(ss, 2, 64);
    ss += __shfl_xor(ss, 4, 64);
    ss += __shfl_xor(ss, 8, 64);
    ss += __shfl_xor(ss, 16, 64);
    if ((lane & 31) == 0) {
      float inv = 1.0f / fmaxf(sqrtf(ss), EPS);
      invs[r] = inv;
      sS[r] = sqrtf(inv);
    }
  }
  __syncthreads();

  {
    int c = t & 127, rh = t >> 7;
    #pragma unroll
    for (int j = 0; j < 16; j++) {
      int r0 = rh * 32 + 2 * j;
      float v0 = xs[r0 * 132 + c] * sS[r0];
      float v1 = xs[(r0 + 1) * 132 + c] * sS[r0 + 1];
      ushort hh0 = f2bf(v0), hh1 = f2bf(v1);
      ushort ll0 = f2bf(v0 - bf2f(hh0)), ll1 = f2bf(v1 - bf2f(hh1));
      ushort2 uh; uh.x = hh0; uh.y = hh1;
      ushort2 ul; ul.x = ll0; ul.y = ll1;
      *(ushort2*)&T[c * TSM + r0] = uh;
      *(ushort2*)&T[c * TSM + 128 + r0] = ul;
    }
  }
  __syncthreads();

  f32x4 acc[8];
  #pragma unroll
  for (int tc = 0; tc < 8; tc++) acc[tc] = (f32x4){0.f, 0.f, 0.f, 0.f};
  #pragma unroll
  for (int ks = 0; ks < 4; ks++) {
    int n0 = ks * 32 + q * 8;
    int cA = w * 16 + m;
    bf16x8 Ah = *(bf16x8*)&T[cA * TSM + n0];
    bf16x8 Al = *(bf16x8*)&T[cA * TSM + 128 + n0];
    #pragma unroll
    for (int tc = 0; tc < 8; tc++) {
      int cB = tc * 16 + m;
      bf16x8 Bh = *(bf16x8*)&T[cB * TSM + n0];
      bf16x8 Bl = *(bf16x8*)&T[cB * TSM + 128 + n0];
      acc[tc] = MFMA16(Ah, Bh, acc[tc]);
      acc[tc] = MFMA16(Ah, Bl, acc[tc]);
      acc[tc] = MFMA16(Al, Bh, acc[tc]);
    }
  }
  if (t < 128) invp[t] = invs[t];
  float* outp = Mpart + ((size_t)mb * CCH + chunk) * 16384;
  #pragma unroll
  for (int tc = 0; tc < 8; tc++)
    #pragma unroll
    for (int rg = 0; rg < 4; rg++) {
      int row = w * 16 + q * 4 + rg;
      outp[row * 128 + tc * 16 + m] = acc[tc][rg];
    }
}

// ---------------------------------------------------------------------------
// Kernel 2: matr — reduce partials -> Mi in PADDED T layout (stride TS=288,
// hi at row*TS+c, lo at row*TS+128+c; pads [256,288) unwritten/unread).
// Blocks >= 1024 precompute W2 = wm^2 hi/lo into W2s (linear 256-stride).
// ---------------------------------------------------------------------------
__global__ __launch_bounds__(256) void matr_kernel(const float* __restrict__ Mpart,
                                                   const float* __restrict__ wm,
                                                   ushort* __restrict__ Mi,
                                                   ushort* __restrict__ W2s) {
  int bid = blockIdx.x;
  if (bid >= 1024) {
    int g2 = (bid - 1024) * 256 + threadIdx.x;   // 0..16383
    int r = g2 >> 7, c = g2 & 127;
    float v = wm[g2];
    float v2 = v * v;
    ushort hi = f2bf(v2);
    W2s[r * 256 + c] = hi;
    W2s[r * 256 + 128 + c] = f2bf(v2 - bf2f(hi));
    return;
  }
  int gid = bid * 256 + threadIdx.x;   // 16*16384
  int mb = gid >> 14;
  int e = gid & 16383;
  int k = e >> 7, h = e & 127;
  const float* p = Mpart + (size_t)mb * CCH * 16384 + e;
  float s = 0.f;
  #pragma unroll
  for (int c = 0; c < CCH; c++) s += p[(size_t)c * 16384];
  ushort hi = f2bf(s);
  Mi[(size_t)mb * (128 * TS) + k * TS + h] = hi;
  Mi[(size_t)mb * (128 * TS) + k * TS + 128 + h] = f2bf(s - bf2f(hi));
}

// ---------------------------------------------------------------------------
// Kernel 3: fused2 — R4 structure (3 barriers, z-swap, sc relayout) with:
//  (1) Mi staged via global_load_lds from the padded Mi (pure linear DMA,
//      9 x 512 x 16B exact; wave-uniform LDS base + per-lane global src);
//  (2) W2 loaded to 32 VGPRs at top, ds_written in the restage section —
//      no global latency between barriers 2 and 3.
// LDS: T 73,728 + sc 18,432 = 92,160 B.
// ---------------------------------------------------------------------------
__global__ __launch_bounds__(512) void fused2_kernel(
    const float* __restrict__ h1, const float* __restrict__ h2,
    const float* __restrict__ inv, const ushort* __restrict__ Mi,
    const ushort* __restrict__ W2s, float* __restrict__ out) {
  __shared__ ushort T[128 * TS];       // 73,728 B
  __shared__ float sc[8 * 16 * 36];    // 18,432 B wave-private y scratch

  int g0 = blockIdx.x * 128;
  int which = g0 >> 14, b = (g0 >> 11) & 7, n0 = g0 & 2047;
  const float* xsrc = which ? h2 : h1;
  const ushort* Msrc = Mi + (size_t)((which ^ 1) * 8 + b) * (128 * TS);
  int t = threadIdx.x;
  int lane = t & 63;

  // stage Mi -> T: padded source mirrors T 1:1, so a linear 73,728-B copy
  // reproduces the padded layout exactly.
  #pragma unroll
  for (int i = 0; i < 9; i++) {
    int u = t + 512 * i;               // 16-B units; 9*512*16 = 73,728 B
#if defined(__has_builtin) && __has_builtin(__builtin_amdgcn_global_load_lds)
    const void* g = (const char*)Msrc + (size_t)u * 16;
    void* l = (char*)&T[0] + (size_t)(u - lane) * 16;   // wave-uniform base
    __builtin_amdgcn_global_load_lds(
        (const __attribute__((address_space(1))) void*)g,
        (__attribute__((address_space(3))) void*)l, 16, 0, 0);
#else
    *(bf16x8*)((char*)&T[0] + (size_t)u * 16) =
        *(const bf16x8*)((const char*)Msrc + (size_t)u * 16);
#endif
  }

  // W2 -> registers (32 VGPRs), issued up front; written to T after bar2.
  bf16x8 w2r[8];
  #pragma unroll
  for (int i = 0; i < 8; i++)
    w2r[i] = *(const bf16x8*)&W2s[(t + 512 * i) * 8];

  int m = lane & 15, q = lane >> 4;
  int w = t >> 6, rb = w * 16;
  const float* xrow = xsrc + ((size_t)b * Nn + n0 + rb + m) * Hh;
  float inv_m = inv[which * BN + b * Nn + n0 + rb + m];

  float xv[4][8];
  #pragma unroll
  for (int ks = 0; ks < 4; ks++) {
    int k0 = ks * 32 + q * 8;
    *(float4*)&xv[ks][0] = *(const float4*)(xrow + k0);
    *(float4*)&xv[ks][4] = *(const float4*)(xrow + k0 + 4);
  }
  __syncthreads();   // bar1: T(Mi) staged (compiler drains vmcnt incl. lds-DMA)

  // ---- phase 1 (transposed): thread (m,q) ends with its own row's y values
  f32x4 z[8];
  #pragma unroll
  for (int nt = 0; nt < 8; nt++) z[nt] = (f32x4){0.f, 0.f, 0.f, 0.f};
  #pragma unroll
  for (int ks = 0; ks < 4; ks++) {
    int k0 = ks * 32 + q * 8;
    bf16x8 xh, xl;
    split8(xv[ks], xh, xl);
    #pragma unroll
    for (int nt = 0; nt < 8; nt++) {
      int cB = nt * 16 + m;
      bf16x8 Bh = *(bf16x8*)&T[cB * TS + k0];
      bf16x8 Bl = *(bf16x8*)&T[cB * TS + 128 + k0];
      z[nt] = MFMA16(Bh, xh, z[nt]);
      z[nt] = MFMA16(Bl, xh, z[nt]);
      z[nt] = MFMA16(Bh, xl, z[nt]);
    }
  }

  // ---- wave-private k-relayout: z (C-layout) -> yv (A-frag layout) ----
  float yv[4][8];
  {
    float* srow = &sc[(w * 16 + m) * 36];
    #pragma unroll
    for (int ks = 0; ks < 4; ks++) {
      f32x4 e = z[2 * ks] * inv_m;       // k-offsets  0..15
      f32x4 o = z[2 * ks + 1] * inv_m;   // k-offsets 16..31
      *(f32x4*)&srow[q * 4] = e;
      *(f32x4*)&srow[16 + q * 4] = o;
      f32x4 r0 = *(f32x4*)&srow[q * 8];
      f32x4 r1 = *(f32x4*)&srow[q * 8 + 4];
      #pragma unroll
      for (int i = 0; i < 4; i++) { yv[ks][i] = r0[i]; yv[ks][4 + i] = r1[i]; }
    }
  }
  __syncthreads();   // bar2: everyone done reading T(Mi)

  // T <- W2 from registers (pure ds_write, no global latency here)
  #pragma unroll
  for (int i = 0; i < 8; i++) {
    int u = t + 512 * i;               // 0..4095
    int row = u >> 5, seg = u & 31;    // seg*8 in [0,256): hi<128, lo>=128
    *(bf16x8*)&T[row * TS + seg * 8] = w2r[i];
  }
  __syncthreads();   // bar3

  // ---- phase 2: fm epilogue ----
  f32x4 aN[8], aX[8], aY[8];
  #pragma unroll
  for (int nt = 0; nt < 8; nt++) {
    aN[nt] = (f32x4){0.f, 0.f, 0.f, 0.f};
    aX[nt] = (f32x4){0.f, 0.f, 0.f, 0.f};
    aY[nt] = (f32x4){0.f, 0.f, 0.f, 0.f};
  }
  #pragma unroll
  for (int ks = 0; ks < 4; ks++) {
    int k0 = ks * 32 + q * 8;
    float pxy[8], pxx[8], pyy[8];
    #pragma unroll
    for (int i = 0; i < 8; i++) {
      float xf = xv[ks][i], yf = yv[ks][i];
      pxy[i] = xf * yf;
      pxx[i] = xf * xf;
      pyy[i] = yf * yf;
    }
    bf16x8 xyh, xyl;
    split8(pxy, xyh, xyl);
    bf16x8 xxh = cvt8(pxx);
    bf16x8 yyh = cvt8(pyy);
    #pragma unroll
    for (int nt = 0; nt < 8; nt++) {
      int cB = nt * 16 + m;
      bf16x8 wh = *(bf16x8*)&T[cB * TS + k0];
      bf16x8 wl = *(bf16x8*)&T[cB * TS + 128 + k0];
      aN[nt] = MFMA16(xyh, wh, aN[nt]);
      aN[nt] = MFMA16(xyh, wl, aN[nt]);
      aN[nt] = MFMA16(xyl, wh, aN[nt]);
      aX[nt] = MFMA16(xxh, wh, aX[nt]);
      aX[nt] = MFMA16(xxh, wl, aX[nt]);
      aY[nt] = MFMA16(yyh, wh, aY[nt]);
      aY[nt] = MFMA16(yyh, wl, aY[nt]);
    }
  }

  float* ob = out + (size_t)g0 * Hh;
  #pragma unroll
  for (int nt = 0; nt < 8; nt++)
    #pragma unroll
    for (int rg = 0; rg < 4; rg++) {
      int row = rb + q * 4 + rg;
      float dx = fmaxf(sqrtf(fmaxf(aX[nt][rg], 0.f)), EPS);
      float dy = fmaxf(sqrtf(fmaxf(aY[nt][rg], 0.f)), EPS);
      ob[(size_t)row * Hh + nt * 16 + m] = aN[nt][rg] / (dx * dy);
    }
}

// ---------------------------------------------------------------------------
extern "C" void kernel_launch(void* const* d_in, const int* in_sizes, int n_in,
                              void* d_out, int out_size, void* d_ws, size_t ws_size,
                              hipStream_t stream) {
  const float* h1 = (const float*)d_in[0];
  const float* h2 = (const float*)d_in[1];
  const float* wm = (const float*)d_in[2];
  float* out = (float*)d_out;

  char* ws = (char*)d_ws;
  float* inv   = (float*)ws;                 // 2*16384*4        = 131,072 B
  ushort* Mi   = (ushort*)(ws + 131072);     // 16*128*288*2     = 1,179,648 B
  ushort* W2s  = (ushort*)(ws + 1310720);    // 128*256*2        = 65,536 B
  float* Mpart = (float*)(ws + 1376256);     // 16*16*16384*4    = 16 MiB

  matp_kernel<<<16 * CCH, 512, 0, stream>>>(h1, h2, inv, Mpart);
  matr_kernel<<<1024 + 64, 256, 0, stream>>>(Mpart, wm, Mi, W2s);
  fused2_kernel<<<2 * BN / 128, 512, 0, stream>>>(h1, h2, inv, Mi, W2s, out);
}